// Round 1
// baseline (203.412 us; speedup 1.0000x reference)
//
#include <hip/hip_runtime.h>

// Depth-4 path signature, D=6, via chunked Chen recursion + tensor-algebra combine.
// Levels flat-concat: L1 [0,6), L2 [6,42), L3 [42,258), L4 [258,1554).
#define SIGSZ 1554
#define NCHUNK 2048

// ---------------------------------------------------------------------------
// Phase 1: one 64-thread block per chunk. S1/S2 in LDS (42 floats), S3/S4 in
// registers distributed so thread t owns (ijk)-groups {t, t+64, t+128, t+192}.
// Per-step update uses the factorization e_k = v^{(x)k}/k!:
//   S4[ijk,l] += G[ijk]*v_l,  G = (vi*vj/24 + S1[i]*vj/6 + S2[ij]/2)*vk + S3[ijk]
//   S3[ijk]   += G2[ij]*vk,   G2 = vi*vj/6 + S1[i]*vj/2 + S2[ij]
//   S2[ij]    += (vi/2 + S1[i])*vj ;  S1[i] += vi
// ---------------------------------------------------------------------------
__global__ __launch_bounds__(64) void sig_chunk(const float* __restrict__ x,
                                                float* __restrict__ out,
                                                int n_inc, int chunk_len) {
  const int c = blockIdx.x;
  const int lane = threadIdx.x;
  const int t0 = c * chunk_len;
  int t1 = t0 + chunk_len; if (t1 > n_inc) t1 = n_inc;

  __shared__ float S12[42];   // [0,6)=S1, [6,42)=S2
  __shared__ float vv[6];
  if (lane < 42) S12[lane] = 0.0f;

  int gi[4], gj[4], gk[4];
  bool gvalid[4];
#pragma unroll
  for (int q = 0; q < 4; ++q) {
    int g = lane + 64 * q;
    gvalid[q] = (g < 216);
    int gg = gvalid[q] ? g : 0;
    gi[q] = gg / 36;
    gj[q] = (gg / 6) % 6;
    gk[q] = gg % 6;
  }
  float s3r[4] = {0.f, 0.f, 0.f, 0.f};
  float s4r[4][6];
#pragma unroll
  for (int q = 0; q < 4; ++q)
#pragma unroll
    for (int l = 0; l < 6; ++l) s4r[q][l] = 0.f;

  const int i2 = lane / 6;   // S2-update role (lane<36)
  const int j2 = lane % 6;

  float xp0=0,xp1=0,xp2=0,xp3=0,xp4=0,xp5=0;
  float nx0=0,nx1=0,nx2=0,nx3=0,nx4=0,nx5=0;
  if (t0 < t1) {
    const float* r0 = x + (size_t)t0 * 6;
    xp0=r0[0]; xp1=r0[1]; xp2=r0[2]; xp3=r0[3]; xp4=r0[4]; xp5=r0[5];
    const float* r1 = x + (size_t)(t0 + 1) * 6;
    nx0=r1[0]; nx1=r1[1]; nx2=r1[2]; nx3=r1[3]; nx4=r1[4]; nx5=r1[5];
  }

  for (int t = t0; t < t1; ++t) {
    const float v0=nx0-xp0, v1=nx1-xp1, v2=nx2-xp2,
                v3=nx3-xp3, v4=nx4-xp4, v5=nx5-xp5;

    // software-pipelined prefetch of row t+2 (valid rows: 0..n_inc)
    float pn0=nx0,pn1=nx1,pn2=nx2,pn3=nx3,pn4=nx4,pn5=nx5;
    if (t + 2 <= n_inc) {
      const float* rn = x + (size_t)(t + 2) * 6;
      pn0=rn[0]; pn1=rn[1]; pn2=rn[2]; pn3=rn[3]; pn4=rn[4]; pn5=rn[5];
    }

    float vsel = v0;
    if (lane == 1) vsel = v1;
    else if (lane == 2) vsel = v2;
    else if (lane == 3) vsel = v3;
    else if (lane == 4) vsel = v4;
    else if (lane == 5) vsel = v5;
    if (lane < 6) vv[lane] = vsel;
    __syncthreads();   // vv visible; prev-iter S12 writes visible

    // ---- read-only phase: new lower-level values into registers ----
    float ns1 = 0.f, ns2 = 0.f;
    if (lane < 6) ns1 = S12[lane] + vsel;
    if (lane < 36) {
      float vi = vv[i2], vj = vv[j2];
      ns2 = S12[6 + lane] + (vi * 0.5f + S12[i2]) * vj;
    }

    // ---- register-resident S3/S4 update (reads old S1,S2 from LDS) ----
#pragma unroll
    for (int q = 0; q < 4; ++q) {
      if (!gvalid[q]) continue;
      float s1v = S12[gi[q]];
      float s2v = S12[6 + gi[q] * 6 + gj[q]];
      float vi = vv[gi[q]], vj = vv[gj[q]], vk = vv[gk[q]];
      float a  = vi * vj;
      float sv = s1v * vj;
      float G2 = a * (1.f/6.f)  + sv * 0.5f      + s2v;
      float in4= a * (1.f/24.f) + sv * (1.f/6.f) + s2v * 0.5f;
      float G  = in4 * vk + s3r[q];      // uses OLD S3
      s3r[q]  += G2 * vk;
      s4r[q][0] += G * v0;
      s4r[q][1] += G * v1;
      s4r[q][2] += G * v2;
      s4r[q][3] += G * v3;
      s4r[q][4] += G * v4;
      s4r[q][5] += G * v5;
    }
    __syncthreads();   // all reads of S12 done
    if (lane < 36) S12[6 + lane] = ns2;
    if (lane < 6)  S12[lane] = ns1;

    xp0=nx0; xp1=nx1; xp2=nx2; xp3=nx3; xp4=nx4; xp5=nx5;
    nx0=pn0; nx1=pn1; nx2=pn2; nx3=pn3; nx4=pn4; nx5=pn5;
  }
  __syncthreads();

  float* ob = out + (size_t)c * SIGSZ;
  if (lane < 42) ob[lane] = S12[lane];
#pragma unroll
  for (int q = 0; q < 4; ++q) {
    if (gvalid[q]) {
      int g = lane + 64 * q;
      ob[42 + g] = s3r[q];
#pragma unroll
      for (int l = 0; l < 6; ++l) ob[258 + g * 6 + l] = s4r[q][l];
    }
  }
}

// ---------------------------------------------------------------------------
// Phase 2: combine `group` consecutive chunk signatures left-to-right per block.
// C^k = A^k + B^k + sum_{j=1..k-1} A^j (x) B^{k-j}   (A = left/earlier)
// Updates A in LDS in decreasing-level order; barriers protect lower-level reads.
// ---------------------------------------------------------------------------
__global__ __launch_bounds__(256) void sig_combine(const float* __restrict__ in,
                                                   float* __restrict__ out,
                                                   int n_in, int group) {
  __shared__ float A[SIGSZ];
  __shared__ float B[SIGSZ];
  const int b = blockIdx.x;
  const int tid = threadIdx.x;
  const int start = b * group;
  int end = start + group; if (end > n_in) end = n_in;

  for (int idx = tid; idx < SIGSZ; idx += 256)
    A[idx] = in[(size_t)start * SIGSZ + idx];
  __syncthreads();

  for (int s = start + 1; s < end; ++s) {
    for (int idx = tid; idx < SIGSZ; idx += 256)
      B[idx] = in[(size_t)s * SIGSZ + idx];
    __syncthreads();

    // Level 4: reads A1..A4 elementwise-disjoint from its own writes (A4)
    for (int idx = tid; idx < 1296; idx += 256) {
      int i  = idx / 216;
      int r  = idx - i * 216;      // jkl
      int r2 = idx % 36;           // kl
      int l  = idx % 6;
      float v = A[258 + idx] + B[258 + idx]
              + A[i]              * B[42 + r]
              + A[6 + idx / 36]   * B[6 + r2]
              + A[42 + idx / 6]   * B[l];
      A[258 + idx] = v;
    }
    __syncthreads();
    // Level 3 (reads old A1,A2)
    if (tid < 216) {
      int i = tid / 36;
      int r = tid - i * 36;        // jl
      int l = tid % 6;
      A[42 + tid] = A[42 + tid] + B[42 + tid]
                  + A[i] * B[6 + r]
                  + A[6 + tid / 6] * B[l];
    }
    __syncthreads();
    // Level 2 (reads old A1)
    if (tid < 36) {
      A[6 + tid] = A[6 + tid] + B[6 + tid] + A[tid / 6] * B[tid % 6];
    }
    __syncthreads();
    // Level 1
    if (tid < 6) A[tid] += B[tid];
    __syncthreads();  // also protects B before next overwrite
  }

  for (int idx = tid; idx < SIGSZ; idx += 256)
    out[(size_t)b * SIGSZ + idx] = A[idx];
}

extern "C" void kernel_launch(void* const* d_in, const int* in_sizes, int n_in,
                              void* d_out, int out_size, void* d_ws, size_t ws_size,
                              hipStream_t stream) {
  const float* x = (const float*)d_in[0];
  const int Lrows = in_sizes[0] / 6;
  const int n_inc = Lrows - 1;

  // shrink chunk count if workspace is tight (needs (P + ceil(P/16)) sigs)
  int P = NCHUNK;
  while (P > 64 &&
         (size_t)(P + (P + 15) / 16) * SIGSZ * sizeof(float) > ws_size)
    P >>= 1;
  const int chunk_len = (n_inc + P - 1) / P;

  float* ws0 = (float*)d_ws;
  float* ws1 = ws0 + (size_t)P * SIGSZ;

  sig_chunk<<<P, 64, 0, stream>>>(x, ws0, n_inc, chunk_len);

  // tree reduction in groups of 16 (P=2048: 2048 -> 128 -> 8 -> 1)
  float* cur = ws0;
  float* other = ws1;
  int n = P;
  while (n > 1) {
    int g = (n <= 16) ? n : 16;
    int nb = (n + g - 1) / g;
    float* dst = (nb == 1) ? (float*)d_out : other;
    sig_combine<<<nb, 256, 0, stream>>>(cur, dst, n, g);
    float* tmp = cur; cur = dst; other = tmp;
    n = nb;
  }
}

// Round 2
// 189.615 us; speedup vs baseline: 1.0728x; 1.0728x over previous
//
#include <hip/hip_runtime.h>

// Depth-4 path signature, D=6. Chunked Chen recursion (register-resident,
// barrier-free) + wave-synchronous tensor-algebra combine tree.
//
// Internal state layout (floats), padded stride 1600 (16B-aligned):
//   L4 [0,1296)  L3 [1296,1512)  L2 [1512,1548)  L1 [1548,1554)
// Final output uses reference layout: L1[0,6) L2[6,42) L3[42,258) L4[258,1554).
#define SIGSZ 1554
#define PSTRIDE 1600
#define OFF4 0
#define OFF3 1296
#define OFF2 1512
#define OFF1 1548

#define WAITLGKM() asm volatile("s_waitcnt lgkmcnt(0)" ::: "memory")

__device__ __forceinline__ float sel6(int idx, float a0, float a1, float a2,
                                      float a3, float a4, float a5) {
  float r = a0;
  r = (idx == 1) ? a1 : r;
  r = (idx == 2) ? a2 : r;
  r = (idx == 3) ? a3 : r;
  r = (idx == 4) ? a4 : r;
  r = (idx == 5) ? a5 : r;
  return r;
}

// ---------------------------------------------------------------------------
// Phase 1: one 64-thread block per chunk; lane p<36 owns (i,j)=(p/6,p%6) and
// keeps S2[ij], S3[ij.], S4[ij..], S1[i] entirely in registers. No LDS, no
// barriers. Row loads are wave-uniform, software-pipelined 2 ahead.
//   S4[ijkl] += G*v_l,  G   = (vi*vj/24 + S1[i]*vj/6 + S2[ij]/2)*vk + S3[ijk]
//   S3[ijk]  += G2*vk,  G2  =  vi*vj/6  + S1[i]*vj/2 + S2[ij]
//   S2[ij]   += (vi/2 + S1[i])*vj ;  S1[i] += vi      (old values on RHS)
// ---------------------------------------------------------------------------
__global__ __launch_bounds__(64) void sig_chunk(const float* __restrict__ x,
                                                float* __restrict__ out,
                                                int n_inc, int chunk_len) {
  const int c = blockIdx.x;
  const int p = threadIdx.x;
  const int t0 = c * chunk_len;
  int t1 = t0 + chunk_len; if (t1 > n_inc) t1 = n_inc;
  const int pc = (p < 36) ? p : 35;      // clamp: lanes 36-63 shadow lane 35
  const int i = pc / 6, j = pc % 6;
  const bool act = (p < 36);

  float s1i = 0.f, s2 = 0.f;
  float s3[6] = {0, 0, 0, 0, 0, 0};
  float s4[6][6];
#pragma unroll
  for (int k = 0; k < 6; ++k)
#pragma unroll
    for (int l = 0; l < 6; ++l) s4[k][l] = 0.f;

  float cr[6], nr[6], pr[6];
#pragma unroll
  for (int m = 0; m < 6; ++m) { cr[m] = 0.f; nr[m] = 0.f; }
  if (t0 < t1) {
    const float2* r0 = (const float2*)(x + (size_t)t0 * 6);
    float2 a0 = r0[0], b0 = r0[1], d0 = r0[2];
    cr[0] = a0.x; cr[1] = a0.y; cr[2] = b0.x; cr[3] = b0.y; cr[4] = d0.x; cr[5] = d0.y;
    const float2* r1 = (const float2*)(x + (size_t)(t0 + 1) * 6);
    float2 a1 = r1[0], b1 = r1[1], d1 = r1[2];
    nr[0] = a1.x; nr[1] = a1.y; nr[2] = b1.x; nr[3] = b1.y; nr[4] = d1.x; nr[5] = d1.y;
  }

  for (int t = t0; t < t1; ++t) {
    float v[6];
#pragma unroll
    for (int m = 0; m < 6; ++m) v[m] = nr[m] - cr[m];

    // prefetch row t+2 (needed only if another iteration follows)
#pragma unroll
    for (int m = 0; m < 6; ++m) pr[m] = nr[m];
    if (t + 2 <= n_inc) {
      const float2* rp = (const float2*)(x + (size_t)(t + 2) * 6);
      float2 a = rp[0], b = rp[1], d = rp[2];
      pr[0] = a.x; pr[1] = a.y; pr[2] = b.x; pr[3] = b.y; pr[4] = d.x; pr[5] = d.y;
    }

    const float vi = sel6(i, v[0], v[1], v[2], v[3], v[4], v[5]);
    const float vj = sel6(j, v[0], v[1], v[2], v[3], v[4], v[5]);
    const float a  = vi * vj;
    const float sv = s1i * vj;
    const float G2  = fmaf(a, 1.f / 6.f,  fmaf(sv, 0.5f,      s2));
    const float in4 = fmaf(a, 1.f / 24.f, fmaf(sv, 1.f / 6.f, s2 * 0.5f));
#pragma unroll
    for (int k = 0; k < 6; ++k) {
      const float vk = v[k];
      const float G = fmaf(in4, vk, s3[k]);   // old S3
      s3[k] = fmaf(G2, vk, s3[k]);
#pragma unroll
      for (int l = 0; l < 6; ++l) s4[k][l] = fmaf(G, v[l], s4[k][l]);
    }
    s2 = fmaf(fmaf(vi, 0.5f, s1i), vj, s2);   // old s1i
    s1i += vi;

#pragma unroll
    for (int m = 0; m < 6; ++m) { cr[m] = nr[m]; nr[m] = pr[m]; }
  }

  float* st = out + (size_t)c * PSTRIDE;
  if (act) {
    float4* o4 = (float4*)(st + OFF4 + pc * 36);
#pragma unroll
    for (int q = 0; q < 9; ++q) {
      float4 w;
      w.x = s4[(q * 4 + 0) / 6][(q * 4 + 0) % 6];
      w.y = s4[(q * 4 + 1) / 6][(q * 4 + 1) % 6];
      w.z = s4[(q * 4 + 2) / 6][(q * 4 + 2) % 6];
      w.w = s4[(q * 4 + 3) / 6][(q * 4 + 3) % 6];
      o4[q] = w;
    }
#pragma unroll
    for (int k = 0; k < 6; ++k) st[OFF3 + pc * 6 + k] = s3[k];
    st[OFF2 + pc] = s2;
    if (j == 0) st[OFF1 + i] = s1i;
  }
}

// ---------------------------------------------------------------------------
// Phase 2: combine `group` consecutive states left-to-right. One 64-thread
// wave per block, wave-synchronous (no s_barrier -> no vmcnt drain; the
// next-B global prefetch stays in flight across the product). A-state in
// registers with the same (i,j) ownership; B staged to LDS.
//   C4[ijkl] = A4 + B4 + A1[i]B3[jkl] + A2[ij]B2[kl] + A3[ijk]B1[l]
//   C3[ijk]  = A3 + B3[ijk] + A1[i]B2[jk] + A2[ij]B1[k]
//   C2[ij]   = A2 + B2[ij] + A1[i]B1[j] ;  C1 = A1 + B1   (old A on RHS)
// ---------------------------------------------------------------------------
__global__ __launch_bounds__(64) void sig_combine(const float* __restrict__ in,
                                                  float* __restrict__ out,
                                                  int n_total, int group,
                                                  int final_out) {
  __shared__ float B[PSTRIDE];
  const int b = blockIdx.x;
  const int p = threadIdx.x;
  const int start = b * group;
  int end = start + group; if (end > n_total) end = n_total;
  const int pc = (p < 36) ? p : 35;
  const int i = pc / 6, j = pc % 6;
  const bool act = (p < 36);

  // per-lane staging slices: float4 at float-offset p*4 + 256*cc, cc<7
  int loff[7]; bool lmask[7];
#pragma unroll
  for (int cc = 0; cc < 7; ++cc) {
    loff[cc] = p * 4 + 256 * cc;
    lmask[cc] = (loff[cc] < SIGSZ);     // lane4/cc6 over-reads into pad: ok
  }

  // ---- load state `start` into LDS, init A registers ----
  float4 r[7];
  {
    const float* s0 = in + (size_t)start * PSTRIDE;
#pragma unroll
    for (int cc = 0; cc < 7; ++cc)
      if (lmask[cc]) r[cc] = *(const float4*)(s0 + loff[cc]);
#pragma unroll
    for (int cc = 0; cc < 7; ++cc)
      if (lmask[cc]) *(float4*)(B + loff[cc]) = r[cc];
  }
  WAITLGKM();
  __builtin_amdgcn_wave_barrier();

  float A4[6][6], A3[6], A1[6];
  float A2_;
  {
    const float4* b4 = (const float4*)(B + OFF4 + pc * 36);
#pragma unroll
    for (int q = 0; q < 9; ++q) {
      float4 w = b4[q];
      A4[(q * 4 + 0) / 6][(q * 4 + 0) % 6] = w.x;
      A4[(q * 4 + 1) / 6][(q * 4 + 1) % 6] = w.y;
      A4[(q * 4 + 2) / 6][(q * 4 + 2) % 6] = w.z;
      A4[(q * 4 + 3) / 6][(q * 4 + 3) % 6] = w.w;
    }
#pragma unroll
    for (int k = 0; k < 6; ++k) A3[k] = B[OFF3 + pc * 6 + k];
    A2_ = B[OFF2 + pc];
#pragma unroll
    for (int l = 0; l < 6; ++l) A1[l] = B[OFF1 + l];
  }
  WAITLGKM();
  __builtin_amdgcn_wave_barrier();

  // prefetch state start+1
  if (start + 1 < end) {
    const float* sp = in + (size_t)(start + 1) * PSTRIDE;
#pragma unroll
    for (int cc = 0; cc < 7; ++cc)
      if (lmask[cc]) r[cc] = *(const float4*)(sp + loff[cc]);
  }

  for (int s = start + 1; s < end; ++s) {
    // previous product's LDS reads are done (results consumed); write new B.
    WAITLGKM();
    __builtin_amdgcn_wave_barrier();
#pragma unroll
    for (int cc = 0; cc < 7; ++cc)
      if (lmask[cc]) *(float4*)(B + loff[cc]) = r[cc];
    // issue next prefetch (vmcnt-tracked; never drained by a barrier)
    if (s + 1 < end) {
      const float* sn = in + (size_t)(s + 1) * PSTRIDE;
#pragma unroll
      for (int cc = 0; cc < 7; ++cc)
        if (lmask[cc]) r[cc] = *(const float4*)(sn + loff[cc]);
    }
    WAITLGKM();                 // ds_writes visible to all lanes
    __builtin_amdgcn_wave_barrier();

    float B1[6];
#pragma unroll
    for (int l = 0; l < 6; ++l) B1[l] = B[OFF1 + l];
    const float a1i = sel6(i, A1[0], A1[1], A1[2], A1[3], A1[4], A1[5]);
    const float b1j = sel6(j, B1[0], B1[1], B1[2], B1[3], B1[4], B1[5]);

    const float* B4r = B + OFF4 + pc * 36;   // B4[i,j,:,:]
    const float* B3j = B + OFF3 + j * 36;    // B3[j,:,:]
    const float* B3ij = B + OFF3 + pc * 6;   // B3[i,j,:]
    const float* B2a = B + OFF2;             // B2[:,:]
    const float* B2j = B + OFF2 + j * 6;     // B2[j,:]

#pragma unroll
    for (int k = 0; k < 6; ++k) {
      const float a3k = A3[k];
#pragma unroll
      for (int l = 0; l < 6; ++l) {
        float t = A4[k][l] + B4r[k * 6 + l];
        t = fmaf(a1i, B3j[k * 6 + l], t);
        t = fmaf(A2_, B2a[k * 6 + l], t);
        A4[k][l] = fmaf(a3k, B1[l], t);
      }
    }
#pragma unroll
    for (int k = 0; k < 6; ++k) {
      float t = A3[k] + B3ij[k];
      t = fmaf(a1i, B2j[k], t);
      A3[k] = fmaf(A2_, B1[k], t);
    }
    A2_ = fmaf(a1i, b1j, A2_ + B[OFF2 + pc]);
#pragma unroll
    for (int l = 0; l < 6; ++l) A1[l] += B1[l];
  }

  const float a1p = sel6(p, A1[0], A1[1], A1[2], A1[3], A1[4], A1[5]);
  if (final_out) {
    // reference layout
    float* o = out;
    if (act) {
#pragma unroll
      for (int k = 0; k < 6; ++k)
#pragma unroll
        for (int l = 0; l < 6; ++l) o[258 + pc * 36 + k * 6 + l] = A4[k][l];
#pragma unroll
      for (int k = 0; k < 6; ++k) o[42 + pc * 6 + k] = A3[k];
      o[6 + pc] = A2_;
    }
    if (p < 6) o[p] = a1p;
  } else {
    float* st = out + (size_t)b * PSTRIDE;
    if (act) {
      float4* o4 = (float4*)(st + OFF4 + pc * 36);
#pragma unroll
      for (int q = 0; q < 9; ++q) {
        float4 w;
        w.x = A4[(q * 4 + 0) / 6][(q * 4 + 0) % 6];
        w.y = A4[(q * 4 + 1) / 6][(q * 4 + 1) % 6];
        w.z = A4[(q * 4 + 2) / 6][(q * 4 + 2) % 6];
        w.w = A4[(q * 4 + 3) / 6][(q * 4 + 3) % 6];
        o4[q] = w;
      }
#pragma unroll
      for (int k = 0; k < 6; ++k) st[OFF3 + pc * 6 + k] = A3[k];
      st[OFF2 + pc] = A2_;
    }
    if (p < 6) st[OFF1 + p] = a1p;
  }
}

extern "C" void kernel_launch(void* const* d_in, const int* in_sizes, int n_in,
                              void* d_out, int out_size, void* d_ws, size_t ws_size,
                              hipStream_t stream) {
  const float* x = (const float*)d_in[0];
  const int Lrows = in_sizes[0] / 6;
  const int n_inc = Lrows - 1;

  int P = 1024;
  while (P > 64 &&
         (size_t)(P + (P + 15) / 16) * PSTRIDE * sizeof(float) > ws_size)
    P >>= 1;
  const int chunk_len = (n_inc + P - 1) / P;

  float* ws0 = (float*)d_ws;
  float* ws1 = ws0 + (size_t)P * PSTRIDE;

  sig_chunk<<<P, 64, 0, stream>>>(x, ws0, n_inc, chunk_len);

  float* cur = ws0;
  float* other = ws1;
  int n = P;
  while (n > 1) {
    const int g = (n <= 16) ? n : 16;
    const int nb = (n + g - 1) / g;
    const int fin = (nb == 1);
    sig_combine<<<nb, 64, 0, stream>>>(cur, fin ? (float*)d_out : other, n, g, fin);
    float* t = cur; cur = other; other = t;
    n = nb;
  }
}

// Round 3
// 188.259 us; speedup vs baseline: 1.0805x; 1.0072x over previous
//
#include <hip/hip_runtime.h>

// Depth-4 path signature, D=6. Chunked Chen recursion (register-resident,
// barrier-free) + wave-synchronous tensor-algebra combine tree.
//
// Internal state layout (floats), padded stride 1600 (16B-aligned):
//   L4 [0,1296)  L3 [1296,1512)  L2 [1512,1548)  L1 [1548,1554)
// Final output uses reference layout: L1[0,6) L2[6,42) L3[42,258) L4[258,1554).
//
// NOTE: __launch_bounds__(64, 1) is load-bearing. Without the ",1" the
// compiler targets ~8 waves/SIMD, caps VGPRs at ~52, and spills the entire
// register-resident signature state to scratch (R2: 50us combine dispatches
// with VALUBusy 0.008% -- pure scratch-latency stall).
#define SIGSZ 1554
#define PSTRIDE 1600
#define OFF4 0
#define OFF3 1296
#define OFF2 1512
#define OFF1 1548

#define WAITLGKM() asm volatile("s_waitcnt lgkmcnt(0)" ::: "memory")

__device__ __forceinline__ float sel6(int idx, float a0, float a1, float a2,
                                      float a3, float a4, float a5) {
  float r = a0;
  r = (idx == 1) ? a1 : r;
  r = (idx == 2) ? a2 : r;
  r = (idx == 3) ? a3 : r;
  r = (idx == 4) ? a4 : r;
  r = (idx == 5) ? a5 : r;
  return r;
}

// ---------------------------------------------------------------------------
// Phase 1: one 64-thread block per chunk; lane p<36 owns (i,j)=(p/6,p%6) and
// keeps S2[ij], S3[ij.], S4[ij..], S1[i] entirely in registers. No LDS, no
// barriers. Row loads are wave-uniform, software-pipelined 2 ahead.
//   S4[ijkl] += G*v_l,  G   = (vi*vj/24 + S1[i]*vj/6 + S2[ij]/2)*vk + S3[ijk]
//   S3[ijk]  += G2*vk,  G2  =  vi*vj/6  + S1[i]*vj/2 + S2[ij]
//   S2[ij]   += (vi/2 + S1[i])*vj ;  S1[i] += vi      (old values on RHS)
// ---------------------------------------------------------------------------
__global__ __launch_bounds__(64, 1) void sig_chunk(const float* __restrict__ x,
                                                   float* __restrict__ out,
                                                   int n_inc, int chunk_len) {
  const int c = blockIdx.x;
  const int p = threadIdx.x;
  const int t0 = c * chunk_len;
  int t1 = t0 + chunk_len; if (t1 > n_inc) t1 = n_inc;
  const int pc = (p < 36) ? p : 35;      // clamp: lanes 36-63 shadow lane 35
  const int i = pc / 6, j = pc % 6;
  const bool act = (p < 36);

  float s1i = 0.f, s2 = 0.f;
  float s3[6] = {0, 0, 0, 0, 0, 0};
  float s4[6][6];
#pragma unroll
  for (int k = 0; k < 6; ++k)
#pragma unroll
    for (int l = 0; l < 6; ++l) s4[k][l] = 0.f;

  float cr[6], nr[6], pr[6];
#pragma unroll
  for (int m = 0; m < 6; ++m) { cr[m] = 0.f; nr[m] = 0.f; }
  if (t0 < t1) {
    const float2* r0 = (const float2*)(x + (size_t)t0 * 6);
    float2 a0 = r0[0], b0 = r0[1], d0 = r0[2];
    cr[0] = a0.x; cr[1] = a0.y; cr[2] = b0.x; cr[3] = b0.y; cr[4] = d0.x; cr[5] = d0.y;
    const float2* r1 = (const float2*)(x + (size_t)(t0 + 1) * 6);
    float2 a1 = r1[0], b1 = r1[1], d1 = r1[2];
    nr[0] = a1.x; nr[1] = a1.y; nr[2] = b1.x; nr[3] = b1.y; nr[4] = d1.x; nr[5] = d1.y;
  }

  for (int t = t0; t < t1; ++t) {
    float v[6];
#pragma unroll
    for (int m = 0; m < 6; ++m) v[m] = nr[m] - cr[m];

    // prefetch row t+2 (needed only if another iteration follows)
#pragma unroll
    for (int m = 0; m < 6; ++m) pr[m] = nr[m];
    if (t + 2 <= n_inc) {
      const float2* rp = (const float2*)(x + (size_t)(t + 2) * 6);
      float2 a = rp[0], b = rp[1], d = rp[2];
      pr[0] = a.x; pr[1] = a.y; pr[2] = b.x; pr[3] = b.y; pr[4] = d.x; pr[5] = d.y;
    }

    const float vi = sel6(i, v[0], v[1], v[2], v[3], v[4], v[5]);
    const float vj = sel6(j, v[0], v[1], v[2], v[3], v[4], v[5]);
    const float a  = vi * vj;
    const float sv = s1i * vj;
    const float G2  = fmaf(a, 1.f / 6.f,  fmaf(sv, 0.5f,      s2));
    const float in4 = fmaf(a, 1.f / 24.f, fmaf(sv, 1.f / 6.f, s2 * 0.5f));
#pragma unroll
    for (int k = 0; k < 6; ++k) {
      const float vk = v[k];
      const float G = fmaf(in4, vk, s3[k]);   // old S3
      s3[k] = fmaf(G2, vk, s3[k]);
#pragma unroll
      for (int l = 0; l < 6; ++l) s4[k][l] = fmaf(G, v[l], s4[k][l]);
    }
    s2 = fmaf(fmaf(vi, 0.5f, s1i), vj, s2);   // old s1i
    s1i += vi;

#pragma unroll
    for (int m = 0; m < 6; ++m) { cr[m] = nr[m]; nr[m] = pr[m]; }
  }

  float* st = out + (size_t)c * PSTRIDE;
  if (act) {
    float4* o4 = (float4*)(st + OFF4 + pc * 36);
#pragma unroll
    for (int q = 0; q < 9; ++q) {
      float4 w;
      w.x = s4[(q * 4 + 0) / 6][(q * 4 + 0) % 6];
      w.y = s4[(q * 4 + 1) / 6][(q * 4 + 1) % 6];
      w.z = s4[(q * 4 + 2) / 6][(q * 4 + 2) % 6];
      w.w = s4[(q * 4 + 3) / 6][(q * 4 + 3) % 6];
      o4[q] = w;
    }
#pragma unroll
    for (int k = 0; k < 6; ++k) st[OFF3 + pc * 6 + k] = s3[k];
    st[OFF2 + pc] = s2;
    if (j == 0) st[OFF1 + i] = s1i;
  }
}

// ---------------------------------------------------------------------------
// Phase 2: combine `group` consecutive states left-to-right. One 64-thread
// wave per block, wave-synchronous (no s_barrier -> no vmcnt drain; the
// next-B global prefetch stays in flight across the product). A-state in
// registers with the same (i,j) ownership; B staged to LDS.
//   C4[ijkl] = A4 + B4 + A1[i]B3[jkl] + A2[ij]B2[kl] + A3[ijk]B1[l]
//   C3[ijk]  = A3 + B3[ijk] + A1[i]B2[jk] + A2[ij]B1[k]
//   C2[ij]   = A2 + B2[ij] + A1[i]B1[j] ;  C1 = A1 + B1   (old A on RHS)
// ---------------------------------------------------------------------------
__global__ __launch_bounds__(64, 1) void sig_combine(const float* __restrict__ in,
                                                     float* __restrict__ out,
                                                     int n_total, int group,
                                                     int final_out) {
  __shared__ float B[PSTRIDE];
  const int b = blockIdx.x;
  const int p = threadIdx.x;
  const int start = b * group;
  int end = start + group; if (end > n_total) end = n_total;
  const int pc = (p < 36) ? p : 35;
  const int i = pc / 6, j = pc % 6;
  const bool act = (p < 36);

  // per-lane staging slices: float4 at float-offset p*4 + 256*cc, cc<7
  int loff[7]; bool lmask[7];
#pragma unroll
  for (int cc = 0; cc < 7; ++cc) {
    loff[cc] = p * 4 + 256 * cc;
    lmask[cc] = (loff[cc] < SIGSZ);     // lane4/cc6 over-reads into pad: ok
  }

  // ---- load state `start` into LDS, init A registers ----
  float4 r[7];
  {
    const float* s0 = in + (size_t)start * PSTRIDE;
#pragma unroll
    for (int cc = 0; cc < 7; ++cc)
      if (lmask[cc]) r[cc] = *(const float4*)(s0 + loff[cc]);
#pragma unroll
    for (int cc = 0; cc < 7; ++cc)
      if (lmask[cc]) *(float4*)(B + loff[cc]) = r[cc];
  }
  WAITLGKM();
  __builtin_amdgcn_wave_barrier();

  float A4[6][6], A3[6], A1[6];
  float A2_;
  {
    const float4* b4 = (const float4*)(B + OFF4 + pc * 36);
#pragma unroll
    for (int q = 0; q < 9; ++q) {
      float4 w = b4[q];
      A4[(q * 4 + 0) / 6][(q * 4 + 0) % 6] = w.x;
      A4[(q * 4 + 1) / 6][(q * 4 + 1) % 6] = w.y;
      A4[(q * 4 + 2) / 6][(q * 4 + 2) % 6] = w.z;
      A4[(q * 4 + 3) / 6][(q * 4 + 3) % 6] = w.w;
    }
#pragma unroll
    for (int k = 0; k < 6; ++k) A3[k] = B[OFF3 + pc * 6 + k];
    A2_ = B[OFF2 + pc];
#pragma unroll
    for (int l = 0; l < 6; ++l) A1[l] = B[OFF1 + l];
  }
  WAITLGKM();
  __builtin_amdgcn_wave_barrier();

  // prefetch state start+1
  if (start + 1 < end) {
    const float* sp = in + (size_t)(start + 1) * PSTRIDE;
#pragma unroll
    for (int cc = 0; cc < 7; ++cc)
      if (lmask[cc]) r[cc] = *(const float4*)(sp + loff[cc]);
  }

  for (int s = start + 1; s < end; ++s) {
    // previous product's LDS reads are done (results consumed); write new B.
    WAITLGKM();
    __builtin_amdgcn_wave_barrier();
#pragma unroll
    for (int cc = 0; cc < 7; ++cc)
      if (lmask[cc]) *(float4*)(B + loff[cc]) = r[cc];
    // issue next prefetch (vmcnt-tracked; never drained by a barrier)
    if (s + 1 < end) {
      const float* sn = in + (size_t)(s + 1) * PSTRIDE;
#pragma unroll
      for (int cc = 0; cc < 7; ++cc)
        if (lmask[cc]) r[cc] = *(const float4*)(sn + loff[cc]);
    }
    WAITLGKM();                 // ds_writes visible to all lanes
    __builtin_amdgcn_wave_barrier();

    float B1[6];
#pragma unroll
    for (int l = 0; l < 6; ++l) B1[l] = B[OFF1 + l];
    const float a1i = sel6(i, A1[0], A1[1], A1[2], A1[3], A1[4], A1[5]);
    const float b1j = sel6(j, B1[0], B1[1], B1[2], B1[3], B1[4], B1[5]);

    const float* B4r = B + OFF4 + pc * 36;   // B4[i,j,:,:]
    const float* B3j = B + OFF3 + j * 36;    // B3[j,:,:]
    const float* B3ij = B + OFF3 + pc * 6;   // B3[i,j,:]
    const float* B2a = B + OFF2;             // B2[:,:]
    const float* B2j = B + OFF2 + j * 6;     // B2[j,:]

#pragma unroll
    for (int k = 0; k < 6; ++k) {
      const float a3k = A3[k];
#pragma unroll
      for (int l = 0; l < 6; ++l) {
        float t = A4[k][l] + B4r[k * 6 + l];
        t = fmaf(a1i, B3j[k * 6 + l], t);
        t = fmaf(A2_, B2a[k * 6 + l], t);
        A4[k][l] = fmaf(a3k, B1[l], t);
      }
    }
#pragma unroll
    for (int k = 0; k < 6; ++k) {
      float t = A3[k] + B3ij[k];
      t = fmaf(a1i, B2j[k], t);
      A3[k] = fmaf(A2_, B1[k], t);
    }
    A2_ = fmaf(a1i, b1j, A2_ + B[OFF2 + pc]);
#pragma unroll
    for (int l = 0; l < 6; ++l) A1[l] += B1[l];
  }

  const float a1p = sel6(p, A1[0], A1[1], A1[2], A1[3], A1[4], A1[5]);
  if (final_out) {
    // reference layout
    float* o = out;
    if (act) {
#pragma unroll
      for (int k = 0; k < 6; ++k)
#pragma unroll
        for (int l = 0; l < 6; ++l) o[258 + pc * 36 + k * 6 + l] = A4[k][l];
#pragma unroll
      for (int k = 0; k < 6; ++k) o[42 + pc * 6 + k] = A3[k];
      o[6 + pc] = A2_;
    }
    if (p < 6) o[p] = a1p;
  } else {
    float* st = out + (size_t)b * PSTRIDE;
    if (act) {
      float4* o4 = (float4*)(st + OFF4 + pc * 36);
#pragma unroll
      for (int q = 0; q < 9; ++q) {
        float4 w;
        w.x = A4[(q * 4 + 0) / 6][(q * 4 + 0) % 6];
        w.y = A4[(q * 4 + 1) / 6][(q * 4 + 1) % 6];
        w.z = A4[(q * 4 + 2) / 6][(q * 4 + 2) % 6];
        w.w = A4[(q * 4 + 3) / 6][(q * 4 + 3) % 6];
        o4[q] = w;
      }
#pragma unroll
      for (int k = 0; k < 6; ++k) st[OFF3 + pc * 6 + k] = A3[k];
      st[OFF2 + pc] = A2_;
    }
    if (p < 6) st[OFF1 + p] = a1p;
  }
}

extern "C" void kernel_launch(void* const* d_in, const int* in_sizes, int n_in,
                              void* d_out, int out_size, void* d_ws, size_t ws_size,
                              hipStream_t stream) {
  const float* x = (const float*)d_in[0];
  const int Lrows = in_sizes[0] / 6;
  const int n_inc = Lrows - 1;

  int P = 1024;
  while (P > 64 &&
         (size_t)(P + (P + 15) / 16) * PSTRIDE * sizeof(float) > ws_size)
    P >>= 1;
  const int chunk_len = (n_inc + P - 1) / P;

  float* ws0 = (float*)d_ws;
  float* ws1 = ws0 + (size_t)P * PSTRIDE;

  sig_chunk<<<P, 64, 0, stream>>>(x, ws0, n_inc, chunk_len);

  float* cur = ws0;
  float* other = ws1;
  int n = P;
  while (n > 1) {
    const int g = (n <= 16) ? n : 16;
    const int nb = (n + g - 1) / g;
    const int fin = (nb == 1);
    sig_combine<<<nb, 64, 0, stream>>>(cur, fin ? (float*)d_out : other, n, g, fin);
    float* t = cur; cur = other; other = t;
    n = nb;
  }
}

// Round 4
// 109.939 us; speedup vs baseline: 1.8502x; 1.7124x over previous
//
#include <hip/hip_runtime.h>

// Depth-4 path signature, D=6. Chunked Chen recursion + tensor-algebra
// combine tree. ALL per-lane state is individually NAMED SCALARS (macro
// generated): R2/R3 showed the compiler leaves private float arrays
// (A4[6][6], s4[6][6], r[7]) in scratch (VGPR_Count=52 with ~90 live floats,
// VALUBusy 0.3%, 50us combine dispatches = serialized scratch fills).
// Named scalars are SSA by construction and must be register-allocated.
//
// State layout (floats), padded stride 1600 (16B-aligned):
//   L4 [0,1296)  L3 [1296,1512)  L2 [1512,1548)  L1 [1548,1554)
// Final output uses reference layout: L1[0,6) L2[6,42) L3[42,258) L4[258,1554).
#define SIGSZ 1554
#define PSTRIDE 1600
#define OFF4 0
#define OFF3 1296
#define OFF2 1512
#define OFF1 1548

#define WAITLGKM() asm volatile("s_waitcnt lgkmcnt(0)" ::: "memory")

// repeat helpers
#define REP6(M) M(0) M(1) M(2) M(3) M(4) M(5)
#define REP6B(M, k) M(k, 0) M(k, 1) M(k, 2) M(k, 3) M(k, 4) M(k, 5)
#define REP36(M) \
  REP6B(M, 0) REP6B(M, 1) REP6B(M, 2) REP6B(M, 3) REP6B(M, 4) REP6B(M, 5)
#define REP7(M) M(0) M(1) M(2) M(3) M(4) M(5) M(6)

__device__ __forceinline__ float sel6(int idx, float a0, float a1, float a2,
                                      float a3, float a4, float a5) {
  float r = a0;
  r = (idx == 1) ? a1 : r;
  r = (idx == 2) ? a2 : r;
  r = (idx == 3) ? a3 : r;
  r = (idx == 4) ? a4 : r;
  r = (idx == 5) ? a5 : r;
  return r;
}

// ---------------------------------------------------------------------------
// Phase 1: one 64-thread block per chunk; lane p<36 owns (i,j)=(p/6,p%6) and
// keeps S2[ij], S3[ij.], S4[ij..], S1[i] in named-scalar registers. No LDS,
// no barriers. Wave-uniform row loads software-pipelined 2 ahead.
//   S4[ijkl] += G*v_l,  G   = (vi*vj/24 + S1[i]*vj/6 + S2[ij]/2)*vk + S3[ijk]
//   S3[ijk]  += G2*vk,  G2  =  vi*vj/6  + S1[i]*vj/2 + S2[ij]
//   S2[ij]   += (vi/2 + S1[i])*vj ;  S1[i] += vi      (old values on RHS)
// ---------------------------------------------------------------------------
__global__ __launch_bounds__(64, 1) void sig_chunk(const float* __restrict__ x,
                                                   float* __restrict__ out,
                                                   int n_inc, int chunk_len) {
  const int c = blockIdx.x;
  const int p = threadIdx.x;
  const int t0 = c * chunk_len;
  int t1 = t0 + chunk_len; if (t1 > n_inc) t1 = n_inc;
  const int pc = (p < 36) ? p : 35;   // lanes 36-63 shadow lane 35
  const int i = pc / 6, j = pc % 6;
  const bool act = (p < 36);

#define DECL_S4(k, l) float s4_##k##_##l = 0.f;
  REP36(DECL_S4)
#undef DECL_S4
#define DECL_S3(k) float s3_##k = 0.f;
  REP6(DECL_S3)
#undef DECL_S3
  float s1i = 0.f, s2 = 0.f;

  float cr0 = 0, cr1 = 0, cr2 = 0, cr3 = 0, cr4 = 0, cr5 = 0;
  float nr0 = 0, nr1 = 0, nr2 = 0, nr3 = 0, nr4 = 0, nr5 = 0;
  if (t0 < t1) {
    const float2* r0 = (const float2*)(x + (size_t)t0 * 6);
    float2 a0 = r0[0], b0 = r0[1], d0 = r0[2];
    cr0 = a0.x; cr1 = a0.y; cr2 = b0.x; cr3 = b0.y; cr4 = d0.x; cr5 = d0.y;
    const float2* r1 = (const float2*)(x + (size_t)(t0 + 1) * 6);
    float2 a1 = r1[0], b1 = r1[1], d1 = r1[2];
    nr0 = a1.x; nr1 = a1.y; nr2 = b1.x; nr3 = b1.y; nr4 = d1.x; nr5 = d1.y;
  }

  for (int t = t0; t < t1; ++t) {
    const float v0 = nr0 - cr0, v1 = nr1 - cr1, v2 = nr2 - cr2;
    const float v3 = nr3 - cr3, v4 = nr4 - cr4, v5 = nr5 - cr5;

    // prefetch row t+2
    float pr0 = nr0, pr1 = nr1, pr2 = nr2, pr3 = nr3, pr4 = nr4, pr5 = nr5;
    if (t + 2 <= n_inc) {
      const float2* rp = (const float2*)(x + (size_t)(t + 2) * 6);
      float2 a = rp[0], b = rp[1], d = rp[2];
      pr0 = a.x; pr1 = a.y; pr2 = b.x; pr3 = b.y; pr4 = d.x; pr5 = d.y;
    }

    const float vi = sel6(i, v0, v1, v2, v3, v4, v5);
    const float vj = sel6(j, v0, v1, v2, v3, v4, v5);
    const float aa = vi * vj;
    const float sv = s1i * vj;
    const float G2  = fmaf(aa, 1.f / 6.f,  fmaf(sv, 0.5f,      s2));
    const float in4 = fmaf(aa, 1.f / 24.f, fmaf(sv, 1.f / 6.f, s2 * 0.5f));
#define MKG(k)                                    \
    const float G_##k = fmaf(in4, v##k, s3_##k);  \
    s3_##k = fmaf(G2, v##k, s3_##k);
    REP6(MKG)
#undef MKG
#define UPD4(k, l) s4_##k##_##l = fmaf(G_##k, v##l, s4_##k##_##l);
    REP36(UPD4)
#undef UPD4
    s2 = fmaf(fmaf(vi, 0.5f, s1i), vj, s2);   // old s1i
    s1i += vi;

    cr0 = nr0; cr1 = nr1; cr2 = nr2; cr3 = nr3; cr4 = nr4; cr5 = nr5;
    nr0 = pr0; nr1 = pr1; nr2 = pr2; nr3 = pr3; nr4 = pr4; nr5 = pr5;
  }

  float* st = out + (size_t)c * PSTRIDE;
  if (act) {
    float4* o4 = (float4*)(st + OFF4 + pc * 36);
    float4 w;
    w.x = s4_0_0; w.y = s4_0_1; w.z = s4_0_2; w.w = s4_0_3; o4[0] = w;
    w.x = s4_0_4; w.y = s4_0_5; w.z = s4_1_0; w.w = s4_1_1; o4[1] = w;
    w.x = s4_1_2; w.y = s4_1_3; w.z = s4_1_4; w.w = s4_1_5; o4[2] = w;
    w.x = s4_2_0; w.y = s4_2_1; w.z = s4_2_2; w.w = s4_2_3; o4[3] = w;
    w.x = s4_2_4; w.y = s4_2_5; w.z = s4_3_0; w.w = s4_3_1; o4[4] = w;
    w.x = s4_3_2; w.y = s4_3_3; w.z = s4_3_4; w.w = s4_3_5; o4[5] = w;
    w.x = s4_4_0; w.y = s4_4_1; w.z = s4_4_2; w.w = s4_4_3; o4[6] = w;
    w.x = s4_4_4; w.y = s4_4_5; w.z = s4_5_0; w.w = s4_5_1; o4[7] = w;
    w.x = s4_5_2; w.y = s4_5_3; w.z = s4_5_4; w.w = s4_5_5; o4[8] = w;
#define ST3(k) st[OFF3 + pc * 6 + k] = s3_##k;
    REP6(ST3)
#undef ST3
    st[OFF2 + pc] = s2;
    if (j == 0) st[OFF1 + i] = s1i;
  }
}

// ---------------------------------------------------------------------------
// Phase 2: combine `group` consecutive states left-to-right. One 64-thread
// wave per block, wave-synchronous (no s_barrier -> no vmcnt drain; next-B
// global prefetch stays in flight across the product). A-state in named
// scalars with the same (i,j) ownership; B staged to LDS.
//   C4[ijkl] = A4 + B4 + A1[i]B3[jkl] + A2[ij]B2[kl] + A3[ijk]B1[l]
//   C3[ijk]  = A3 + B3[ijk] + A1[i]B2[jk] + A2[ij]B1[k]
//   C2[ij]   = A2 + B2[ij] + A1[i]B1[j] ;  C1 = A1 + B1   (old A on RHS)
// ---------------------------------------------------------------------------
__global__ __launch_bounds__(64, 1) void sig_combine(const float* __restrict__ in,
                                                     float* __restrict__ out,
                                                     int n_total, int group,
                                                     int final_out) {
  __shared__ float B[PSTRIDE];
  const int b = blockIdx.x;
  const int p = threadIdx.x;
  const int start = b * group;
  int end = start + group; if (end > n_total) end = n_total;
  const int pc = (p < 36) ? p : 35;
  const int i = pc / 6, j = pc % 6;
  const bool act = (p < 36);

  // per-lane staging slices: float4 at float-offset p*4 + 256*cc, cc<7
#define DECL_L(cc)                          \
  const int loff##cc = p * 4 + 256 * cc;    \
  const bool lm##cc = (loff##cc < SIGSZ);
  REP7(DECL_L)
#undef DECL_L
#define DECL_R(cc) float4 r_##cc = {0.f, 0.f, 0.f, 0.f};
  REP7(DECL_R)
#undef DECL_R

  // ---- stage state `start` into LDS, init A registers ----
  {
    const float* s0 = in + (size_t)start * PSTRIDE;
#define LDG0(cc) if (lm##cc) r_##cc = *(const float4*)(s0 + loff##cc);
    REP7(LDG0)
#undef LDG0
#define STB0(cc) if (lm##cc) *(float4*)(B + loff##cc) = r_##cc;
    REP7(STB0)
#undef STB0
  }
  WAITLGKM();
  __builtin_amdgcn_wave_barrier();

#define DECL_A4(k, l) float a4_##k##_##l = B[OFF4 + pc * 36 + k * 6 + l];
  REP36(DECL_A4)
#undef DECL_A4
#define DECL_A3(k) float a3_##k = B[OFF3 + pc * 6 + k];
  REP6(DECL_A3)
#undef DECL_A3
  float A2_ = B[OFF2 + pc];
#define DECL_A1(k) float a1_##k = B[OFF1 + k];
  REP6(DECL_A1)
#undef DECL_A1
  WAITLGKM();
  __builtin_amdgcn_wave_barrier();

  // prefetch state start+1
  if (start + 1 < end) {
    const float* sp = in + (size_t)(start + 1) * PSTRIDE;
#define LDGP(cc) if (lm##cc) r_##cc = *(const float4*)(sp + loff##cc);
    REP7(LDGP)
#undef LDGP
  }

  for (int s = start + 1; s < end; ++s) {
    // previous product's LDS reads are complete; write new B.
    WAITLGKM();
    __builtin_amdgcn_wave_barrier();
#define STB(cc) if (lm##cc) *(float4*)(B + loff##cc) = r_##cc;
    REP7(STB)
#undef STB
    // issue next prefetch (vmcnt-tracked; never drained by a barrier)
    if (s + 1 < end) {
      const float* sn = in + (size_t)(s + 1) * PSTRIDE;
#define LDGN(cc) if (lm##cc) r_##cc = *(const float4*)(sn + loff##cc);
      REP7(LDGN)
#undef LDGN
    }
    WAITLGKM();                 // ds_writes visible wave-wide
    __builtin_amdgcn_wave_barrier();

#define LDB1(k) const float b1_##k = B[OFF1 + k];
    REP6(LDB1)
#undef LDB1
    const float a1i = sel6(i, a1_0, a1_1, a1_2, a1_3, a1_4, a1_5);
    const float b1j = sel6(j, b1_0, b1_1, b1_2, b1_3, b1_4, b1_5);

    const int base4  = OFF4 + pc * 36;   // B4[i,j,:,:]
    const int base3j = OFF3 + j * 36;    // B3[j,:,:]
    const int base3ij = OFF3 + pc * 6;   // B3[i,j,:]
    const int base2j = OFF2 + j * 6;     // B2[j,:]

#define C4(k, l)                                                     \
    a4_##k##_##l = fmaf(a3_##k, b1_##l,                              \
                   fmaf(A2_, B[OFF2 + k * 6 + l],                    \
                   fmaf(a1i, B[base3j + k * 6 + l],                  \
                        a4_##k##_##l + B[base4 + k * 6 + l])));
    REP36(C4)
#undef C4
#define C3(k)                                                        \
    a3_##k = fmaf(A2_, b1_##k,                                       \
             fmaf(a1i, B[base2j + k], a3_##k + B[base3ij + k]));
    REP6(C3)
#undef C3
    A2_ = fmaf(a1i, b1j, A2_ + B[OFF2 + pc]);
#define C1(k) a1_##k += b1_##k;
    REP6(C1)
#undef C1
  }

  const float a1p = sel6(p, a1_0, a1_1, a1_2, a1_3, a1_4, a1_5);
  if (final_out) {
    float* o = out;   // reference layout
    if (act) {
#define SO4(k, l) o[258 + pc * 36 + k * 6 + l] = a4_##k##_##l;
      REP36(SO4)
#undef SO4
#define SO3(k) o[42 + pc * 6 + k] = a3_##k;
      REP6(SO3)
#undef SO3
      o[6 + pc] = A2_;
    }
    if (p < 6) o[p] = a1p;
  } else {
    float* st = out + (size_t)b * PSTRIDE;
    if (act) {
      float4* o4 = (float4*)(st + OFF4 + pc * 36);
      float4 w;
      w.x = a4_0_0; w.y = a4_0_1; w.z = a4_0_2; w.w = a4_0_3; o4[0] = w;
      w.x = a4_0_4; w.y = a4_0_5; w.z = a4_1_0; w.w = a4_1_1; o4[1] = w;
      w.x = a4_1_2; w.y = a4_1_3; w.z = a4_1_4; w.w = a4_1_5; o4[2] = w;
      w.x = a4_2_0; w.y = a4_2_1; w.z = a4_2_2; w.w = a4_2_3; o4[3] = w;
      w.x = a4_2_4; w.y = a4_2_5; w.z = a4_3_0; w.w = a4_3_1; o4[4] = w;
      w.x = a4_3_2; w.y = a4_3_3; w.z = a4_3_4; w.w = a4_3_5; o4[5] = w;
      w.x = a4_4_0; w.y = a4_4_1; w.z = a4_4_2; w.w = a4_4_3; o4[6] = w;
      w.x = a4_4_4; w.y = a4_4_5; w.z = a4_5_0; w.w = a4_5_1; o4[7] = w;
      w.x = a4_5_2; w.y = a4_5_3; w.z = a4_5_4; w.w = a4_5_5; o4[8] = w;
#define SP3(k) st[OFF3 + pc * 6 + k] = a3_##k;
      REP6(SP3)
#undef SP3
      st[OFF2 + pc] = A2_;
    }
    if (p < 6) st[OFF1 + p] = a1p;
  }
}

extern "C" void kernel_launch(void* const* d_in, const int* in_sizes, int n_in,
                              void* d_out, int out_size, void* d_ws, size_t ws_size,
                              hipStream_t stream) {
  const float* x = (const float*)d_in[0];
  const int Lrows = in_sizes[0] / 6;
  const int n_inc = Lrows - 1;

  int P = 1024;
  while (P > 64 &&
         (size_t)(P + (P + 15) / 16) * PSTRIDE * sizeof(float) > ws_size)
    P >>= 1;
  const int chunk_len = (n_inc + P - 1) / P;

  float* ws0 = (float*)d_ws;
  float* ws1 = ws0 + (size_t)P * PSTRIDE;

  sig_chunk<<<P, 64, 0, stream>>>(x, ws0, n_inc, chunk_len);

  float* cur = ws0;
  float* other = ws1;
  int n = P;
  while (n > 1) {
    const int g = (n <= 16) ? n : 16;
    const int nb = (n + g - 1) / g;
    const int fin = (nb == 1);
    sig_combine<<<nb, 64, 0, stream>>>(cur, fin ? (float*)d_out : other, n, g, fin);
    float* t = cur; cur = other; other = t;
    n = nb;
  }
}

// Round 5
// 94.307 us; speedup vs baseline: 2.1569x; 1.1657x over previous
//
#include <hip/hip_runtime.h>

// Depth-4 path signature, D=6. Chunked Chen recursion + tensor-algebra
// combine tree. All per-lane state is NAMED SCALARS (R2-R4: private arrays
// stay in scratch; named scalars fixed it, 188->110us).
//
// R5: (1) sig_chunk stages its x rows into LDS once, loop reads rows from
// LDS (global-load latency was serialized into the 98-step chain);
// (2) sig_combine is lane-independent: lane owns (i,j,k), keeps its A-slice
// + redundant A2[ij]/A1[:] in regs, B-slices prefetched global->regs two
// products ahead. No LDS, no barriers in combine.
//
// State layout (floats), padded stride 1600 (16B-aligned):
//   L4 [0,1296)  L3 [1296,1512)  L2 [1512,1548)  L1 [1548,1554)
// Final output uses reference layout: L1[0,6) L2[6,42) L3[42,258) L4[258,1554).
#define SIGSZ 1554
#define PSTRIDE 1600
#define OFF4 0
#define OFF3 1296
#define OFF2 1512
#define OFF1 1548
#define MAXROWS 80   // LDS row capacity in sig_chunk (chunk_len <= 79)

#define REP6(M) M(0) M(1) M(2) M(3) M(4) M(5)
#define REP6B(M, k) M(k, 0) M(k, 1) M(k, 2) M(k, 3) M(k, 4) M(k, 5)
#define REP36(M) \
  REP6B(M, 0) REP6B(M, 1) REP6B(M, 2) REP6B(M, 3) REP6B(M, 4) REP6B(M, 5)

__device__ __forceinline__ float sel6(int idx, float a0, float a1, float a2,
                                      float a3, float a4, float a5) {
  float r = a0;
  r = (idx == 1) ? a1 : r;
  r = (idx == 2) ? a2 : r;
  r = (idx == 3) ? a3 : r;
  r = (idx == 4) ? a4 : r;
  r = (idx == 5) ? a5 : r;
  return r;
}

// ---------------------------------------------------------------------------
// Phase 1: one 64-thread block per chunk; lane p<36 owns (i,j)=(p/6,p%6).
// S2[ij], S3[ij.], S4[ij..], S1[i] in named-scalar registers. x rows staged
// to LDS once; loop is branch-free with 2-row LDS prefetch slack.
//   S4[ijkl] += G*v_l,  G   = (vi*vj/24 + S1[i]*vj/6 + S2[ij]/2)*vk + S3[ijk]
//   S3[ijk]  += G2*vk,  G2  =  vi*vj/6  + S1[i]*vj/2 + S2[ij]
//   S2[ij]   += (vi/2 + S1[i])*vj ;  S1[i] += vi      (old values on RHS)
// ---------------------------------------------------------------------------
__global__ __launch_bounds__(64, 1) void sig_chunk(const float* __restrict__ x,
                                                   float* __restrict__ out,
                                                   int n_inc, int chunk_len) {
  __shared__ float xs[MAXROWS * 6];
  const int c = blockIdx.x;
  const int p = threadIdx.x;
  const int t0 = c * chunk_len;
  int t1 = t0 + chunk_len; if (t1 > n_inc) t1 = n_inc;
  const int steps = (t1 > t0) ? (t1 - t0) : 0;
  const int pc = (p < 36) ? p : 35;
  const int i = pc / 6, j = pc % 6;
  const bool act = (p < 36);

  // ---- stage rows t0..t0+steps (steps+1 rows) into LDS ----
  const int nfl = (steps > 0) ? (steps + 1) * 6 : 0;
  for (int idx = p; idx < nfl; idx += 64) xs[idx] = x[(size_t)t0 * 6 + idx];
  __syncthreads();

#define DECL_S4(k, l) float s4_##k##_##l = 0.f;
  REP36(DECL_S4)
#undef DECL_S4
#define DECL_S3(k) float s3_##k = 0.f;
  REP6(DECL_S3)
#undef DECL_S3
  float s1i = 0.f, s2 = 0.f;

  float cr0 = 0, cr1 = 0, cr2 = 0, cr3 = 0, cr4 = 0, cr5 = 0;
  float nr0 = 0, nr1 = 0, nr2 = 0, nr3 = 0, nr4 = 0, nr5 = 0;
  if (steps > 0) {
    const float2* q0 = (const float2*)(xs);
    float2 a0 = q0[0], b0 = q0[1], d0 = q0[2];
    cr0 = a0.x; cr1 = a0.y; cr2 = b0.x; cr3 = b0.y; cr4 = d0.x; cr5 = d0.y;
    const float2* q1 = (const float2*)(xs + 6);
    float2 a1 = q1[0], b1 = q1[1], d1 = q1[2];
    nr0 = a1.x; nr1 = a1.y; nr2 = b1.x; nr3 = b1.y; nr4 = d1.x; nr5 = d1.y;
  }

  for (int r = 0; r < steps; ++r) {
    const float v0 = nr0 - cr0, v1 = nr1 - cr1, v2 = nr2 - cr2;
    const float v3 = nr3 - cr3, v4 = nr4 - cr4, v5 = nr5 - cr5;

    // branch-free LDS prefetch of row r+2 (clamped to last staged row)
    int ro = r + 2; ro = (ro > steps) ? steps : ro;
    const float2* qp = (const float2*)(xs + ro * 6);
    const float2 pa = qp[0], pb = qp[1], pd = qp[2];

    const float vi = sel6(i, v0, v1, v2, v3, v4, v5);
    const float vj = sel6(j, v0, v1, v2, v3, v4, v5);
    const float aa = vi * vj;
    const float sv = s1i * vj;
    const float G2  = fmaf(aa, 1.f / 6.f,  fmaf(sv, 0.5f,      s2));
    const float in4 = fmaf(aa, 1.f / 24.f, fmaf(sv, 1.f / 6.f, s2 * 0.5f));
#define MKG(k)                                    \
    const float G_##k = fmaf(in4, v##k, s3_##k);  \
    s3_##k = fmaf(G2, v##k, s3_##k);
    REP6(MKG)
#undef MKG
#define UPD4(k, l) s4_##k##_##l = fmaf(G_##k, v##l, s4_##k##_##l);
    REP36(UPD4)
#undef UPD4
    s2 = fmaf(fmaf(vi, 0.5f, s1i), vj, s2);   // old s1i
    s1i += vi;

    cr0 = nr0; cr1 = nr1; cr2 = nr2; cr3 = nr3; cr4 = nr4; cr5 = nr5;
    nr0 = pa.x; nr1 = pa.y; nr2 = pb.x; nr3 = pb.y; nr4 = pd.x; nr5 = pd.y;
  }

  float* st = out + (size_t)c * PSTRIDE;
  if (act) {
    float4* o4 = (float4*)(st + OFF4 + pc * 36);
    float4 w;
    w.x = s4_0_0; w.y = s4_0_1; w.z = s4_0_2; w.w = s4_0_3; o4[0] = w;
    w.x = s4_0_4; w.y = s4_0_5; w.z = s4_1_0; w.w = s4_1_1; o4[1] = w;
    w.x = s4_1_2; w.y = s4_1_3; w.z = s4_1_4; w.w = s4_1_5; o4[2] = w;
    w.x = s4_2_0; w.y = s4_2_1; w.z = s4_2_2; w.w = s4_2_3; o4[3] = w;
    w.x = s4_2_4; w.y = s4_2_5; w.z = s4_3_0; w.w = s4_3_1; o4[4] = w;
    w.x = s4_3_2; w.y = s4_3_3; w.z = s4_3_4; w.w = s4_3_5; o4[5] = w;
    w.x = s4_4_0; w.y = s4_4_1; w.z = s4_4_2; w.w = s4_4_3; o4[6] = w;
    w.x = s4_4_4; w.y = s4_4_5; w.z = s4_5_0; w.w = s4_5_1; o4[7] = w;
    w.x = s4_5_2; w.y = s4_5_3; w.z = s4_5_4; w.w = s4_5_5; o4[8] = w;
#define ST3(k) st[OFF3 + pc * 6 + k] = s3_##k;
    REP6(ST3)
#undef ST3
    st[OFF2 + pc] = s2;
    if (j == 0) st[OFF1 + i] = s1i;
  }
}

// ---------------------------------------------------------------------------
// Phase 2: combine `group` consecutive states left-to-right. 256-thread
// blocks; lane t<216 owns triple (i,j,k) = (t/36, (t/6)%6, t%6), keeping
// C4[ijk,:] (6), C3[ijk], and REDUNDANT copies of C2[ij], C1[:] in regs.
// Every lane is fully independent: B-slices are loaded straight from global
// (L2/LLC-resident) into named registers, ping-pong prefetched 2 products
// ahead. No LDS, no barriers.
//   C4[ijk,l] = A4 + B4[ijk,l] + A1[i]B3[jk,l] + A2[ij]B2[k,l] + A3[ijk]B1[l]
//   C3[ijk]   = A3 + B3[ijk] + A1[i]B2[jk] + A2[ij]B1[k]
//   C2[ij]    = A2 + B2[ij] + A1[i]B1[j] ;  C1 = A1 + B1   (old A on RHS)
// ---------------------------------------------------------------------------

// 31 named scalars per prefetch set
#define DECLSET(S)                                                  \
  float S##b4_0, S##b4_1, S##b4_2, S##b4_3, S##b4_4, S##b4_5;       \
  float S##b3r_0, S##b3r_1, S##b3r_2, S##b3r_3, S##b3r_4, S##b3r_5; \
  float S##b2r_0, S##b2r_1, S##b2r_2, S##b2r_3, S##b2r_4, S##b2r_5; \
  float S##b1_0, S##b1_1, S##b1_2, S##b1_3, S##b1_4, S##b1_5;       \
  float S##b2ij, S##b2jk, S##b3ijk, S##b1k, S##b1j;

#define LOADSET(S, bp) {                                            \
  const float2* q4 = (const float2*)((bp) + oB4);                   \
  float2 u0 = q4[0], u1 = q4[1], u2 = q4[2];                        \
  S##b4_0 = u0.x; S##b4_1 = u0.y; S##b4_2 = u1.x;                   \
  S##b4_3 = u1.y; S##b4_4 = u2.x; S##b4_5 = u2.y;                   \
  const float2* q3 = (const float2*)((bp) + oB3r);                  \
  float2 w0 = q3[0], w1 = q3[1], w2 = q3[2];                        \
  S##b3r_0 = w0.x; S##b3r_1 = w0.y; S##b3r_2 = w1.x;                \
  S##b3r_3 = w1.y; S##b3r_4 = w2.x; S##b3r_5 = w2.y;                \
  const float2* q2 = (const float2*)((bp) + oB2r);                  \
  float2 y0 = q2[0], y1 = q2[1], y2 = q2[2];                        \
  S##b2r_0 = y0.x; S##b2r_1 = y0.y; S##b2r_2 = y1.x;                \
  S##b2r_3 = y1.y; S##b2r_4 = y2.x; S##b2r_5 = y2.y;                \
  const float2* q1 = (const float2*)((bp) + OFF1);                  \
  float2 z0 = q1[0], z1 = q1[1], z2 = q1[2];                        \
  S##b1_0 = z0.x; S##b1_1 = z0.y; S##b1_2 = z1.x;                   \
  S##b1_3 = z1.y; S##b1_4 = z2.x; S##b1_5 = z2.y;                   \
  S##b2ij = (bp)[oB2ij]; S##b2jk = (bp)[oB2jk];                     \
  S##b3ijk = (bp)[oB3ijk];                                          \
  S##b1k = (bp)[oB1k]; S##b1j = (bp)[oB1j];                         \
}

#define PROD(S) {                                                   \
  const float a1i = sel6(i_, a1_0, a1_1, a1_2, a1_3, a1_4, a1_5);   \
  a4_0 = fmaf(a3, S##b1_0, fmaf(a2, S##b2r_0,                       \
         fmaf(a1i, S##b3r_0, a4_0 + S##b4_0)));                     \
  a4_1 = fmaf(a3, S##b1_1, fmaf(a2, S##b2r_1,                       \
         fmaf(a1i, S##b3r_1, a4_1 + S##b4_1)));                     \
  a4_2 = fmaf(a3, S##b1_2, fmaf(a2, S##b2r_2,                       \
         fmaf(a1i, S##b3r_2, a4_2 + S##b4_2)));                     \
  a4_3 = fmaf(a3, S##b1_3, fmaf(a2, S##b2r_3,                       \
         fmaf(a1i, S##b3r_3, a4_3 + S##b4_3)));                     \
  a4_4 = fmaf(a3, S##b1_4, fmaf(a2, S##b2r_4,                       \
         fmaf(a1i, S##b3r_4, a4_4 + S##b4_4)));                     \
  a4_5 = fmaf(a3, S##b1_5, fmaf(a2, S##b2r_5,                       \
         fmaf(a1i, S##b3r_5, a4_5 + S##b4_5)));                     \
  a3 = fmaf(a2, S##b1k, fmaf(a1i, S##b2jk, a3 + S##b3ijk));         \
  a2 = fmaf(a1i, S##b1j, a2 + S##b2ij);                             \
  a1_0 += S##b1_0; a1_1 += S##b1_1; a1_2 += S##b1_2;                \
  a1_3 += S##b1_3; a1_4 += S##b1_4; a1_5 += S##b1_5;                \
}

__global__ __launch_bounds__(256, 1) void sig_combine(const float* __restrict__ in,
                                                      float* __restrict__ out,
                                                      int n_total, int group,
                                                      int final_out) {
  const int b = blockIdx.x;
  const int p = threadIdx.x;
  const int start = b * group;
  int end = start + group; if (end > n_total) end = n_total;
  const int tc = (p < 216) ? p : 215;
  const bool act = (p < 216);
  const int k_ = tc % 6;
  const int ij = tc / 6;
  const int j_ = ij % 6;
  const int i_ = ij / 6;

  // loop-invariant element offsets
  const int oB4 = OFF4 + tc * 6;
  const int oB3r = OFF3 + (j_ * 6 + k_) * 6;
  const int oB2r = OFF2 + k_ * 6;
  const int oB2ij = OFF2 + ij;
  const int oB2jk = OFF2 + j_ * 6 + k_;
  const int oB3ijk = OFF3 + tc;
  const int oB1k = OFF1 + k_;
  const int oB1j = OFF1 + j_;

  // ---- init A from state `start` ----
  const float* sp0 = in + (size_t)start * PSTRIDE;
  float a4_0, a4_1, a4_2, a4_3, a4_4, a4_5;
  {
    const float2* q4 = (const float2*)(sp0 + oB4);
    float2 u0 = q4[0], u1 = q4[1], u2 = q4[2];
    a4_0 = u0.x; a4_1 = u0.y; a4_2 = u1.x;
    a4_3 = u1.y; a4_4 = u2.x; a4_5 = u2.y;
  }
  float a3 = sp0[oB3ijk];
  float a2 = sp0[oB2ij];
  float a1_0, a1_1, a1_2, a1_3, a1_4, a1_5;
  {
    const float2* q1 = (const float2*)(sp0 + OFF1);
    float2 z0 = q1[0], z1 = q1[1], z2 = q1[2];
    a1_0 = z0.x; a1_1 = z0.y; a1_2 = z1.x;
    a1_3 = z1.y; a1_4 = z2.x; a1_5 = z2.y;
  }

  DECLSET(A)
  DECLSET(B)

  int s = start + 1;
  {
    const int sa = (s < end) ? s : (end - 1);
    LOADSET(A, in + (size_t)sa * PSTRIDE)
    const int sb = (s + 1 < end) ? (s + 1) : (end - 1);
    LOADSET(B, in + (size_t)sb * PSTRIDE)
  }
  while (s + 1 < end) {
    PROD(A)
    {
      const int sn = (s + 2 < end) ? (s + 2) : (end - 1);
      LOADSET(A, in + (size_t)sn * PSTRIDE)
    }
    PROD(B)
    {
      const int sn = (s + 3 < end) ? (s + 3) : (end - 1);
      LOADSET(B, in + (size_t)sn * PSTRIDE)
    }
    s += 2;
  }
  if (s < end) { PROD(A) }

  const float a1p = sel6(p, a1_0, a1_1, a1_2, a1_3, a1_4, a1_5);
  if (final_out) {
    float* o = out;   // reference layout: L1 0, L2 6, L3 42, L4 258
    if (act) {
      float2* o2 = (float2*)(o + 258 + tc * 6);
      float2 w;
      w.x = a4_0; w.y = a4_1; o2[0] = w;
      w.x = a4_2; w.y = a4_3; o2[1] = w;
      w.x = a4_4; w.y = a4_5; o2[2] = w;
      o[42 + tc] = a3;
      if (k_ == 0) o[6 + ij] = a2;
    }
    if (p < 6) o[p] = a1p;
  } else {
    float* st = out + (size_t)b * PSTRIDE;
    if (act) {
      float2* o2 = (float2*)(st + oB4);
      float2 w;
      w.x = a4_0; w.y = a4_1; o2[0] = w;
      w.x = a4_2; w.y = a4_3; o2[1] = w;
      w.x = a4_4; w.y = a4_5; o2[2] = w;
      st[oB3ijk] = a3;
      if (k_ == 0) st[oB2ij] = a2;
    }
    if (p < 6) st[OFF1 + p] = a1p;
  }
}

extern "C" void kernel_launch(void* const* d_in, const int* in_sizes, int n_in,
                              void* d_out, int out_size, void* d_ws, size_t ws_size,
                              hipStream_t stream) {
  const float* x = (const float*)d_in[0];
  const int Lrows = in_sizes[0] / 6;
  const int n_inc = Lrows - 1;

  int P = 2048;
  int chunk_len = (n_inc + P - 1) / P;
  if (chunk_len > MAXROWS - 1) {           // keep LDS staging in bounds
    chunk_len = MAXROWS - 1;
    P = (n_inc + chunk_len - 1) / chunk_len;
  }

  float* ws0 = (float*)d_ws;
  float* ws1 = ws0 + (size_t)P * PSTRIDE;

  sig_chunk<<<P, 64, 0, stream>>>(x, ws0, n_inc, chunk_len);

  float* cur = ws0;
  float* other = ws1;
  int n = P;
  while (n > 1) {
    const int g = (n <= 16) ? n : 16;
    const int nb = (n + g - 1) / g;
    const int fin = (nb == 1);
    sig_combine<<<nb, 256, 0, stream>>>(cur, fin ? (float*)d_out : other, n, g, fin);
    float* t = cur; cur = other; other = t;
    n = nb;
  }
}